// Round 7
// baseline (1254.506 us; speedup 1.0000x reference)
//
#include <hip/hip_runtime.h>

// Flow attention: B=8, L=8192, H=8, D=64, fp32 in/out.
// Pass split = dependency-forced minimum HBM traffic (~804 MB):
//   P1: read k (cached)   -> ksum (column sums of sigmoid(k))
//   P2: read q (cached)   -> qsum, qsi (column sums of sigmoid(q) and qn)
//   P3: read k,v (nt)     -> so, kso, SE, unnormalized kv outer-product
//   P4: read q (nt)       -> recompute si/qn per row in-wave (LDS transpose),
//                            sa, out = sa * (Lk/SE) * qn.kv  (nt store)
// Cache strategy: k and q are each read twice (P1->P3, P2->P4); v/out are
// single-use. nt hints keep the reused streams resident in the 256 MB L3.
constexpr int B = 8, L = 8192, H = 8, D = 64, NH = B * H;
constexpr float FEPS = 1e-6f;

constexpr int CHUNKS = 16;
constexpr int ROWS_PER_WAVE = L / (CHUNKS * 4);   // 128
constexpr int GROUPS = ROWS_PER_WAVE / 4;         // 32

// ws layout (floats):
constexpr int OFF_QSUM = 0;            // [NH][64] sum_l sigmoid(q)
constexpr int OFF_KSUM = 4096;         // [NH][64] sum_l sigmoid(k)
constexpr int OFF_QSI  = 8192;         // [NH][64] sum_l sigmoid(q)*si
constexpr int OFF_KSO  = 12288;        // [NH][64] sum_l sigmoid(k)*so
constexpr int OFF_SE   = 16384;        // [NH]     sum_l exp(clip(cs))
constexpr int OFF_KV   = 16448;        // [NH][64][64] unnormalized kv
constexpr int WS_FLOATS = OFF_KV + NH * D * D;    // 278592 floats ~ 1.06 MB

typedef float vf4 __attribute__((ext_vector_type(4)));

__device__ __forceinline__ vf4 ntload4(const vf4* p) {
  return __builtin_nontemporal_load(p);
}

__device__ __forceinline__ float sigm(float x) {
  // element-wise: fast rcp is ~1e-5 abs error on (0,1) -- safe
  return __builtin_amdgcn_rcpf(1.0f + __expf(-x));
}

// reduce within each 16-lane subgroup (one row)
#define RED16(t) { t += __shfl_xor(t, 1); t += __shfl_xor(t, 2); \
                   t += __shfl_xor(t, 4); t += __shfl_xor(t, 8); }
// reduce across the 4 subgroups (full wave, per-dq totals)
#define REDW(t)  { t += __shfl_xor(t, 16); t += __shfl_xor(t, 32); }

// P1: ksum[d] = sum_l sigmoid(k[l,d]).  (k only: 134 MB, regular -> primes L3)
__global__ __launch_bounds__(256) void p1_ksum(const float* __restrict__ kp,
                                               float* __restrict__ ws) {
  __shared__ float red[4][16][4];
  const int bid = blockIdx.x, nh = bid / CHUNKS, chunk = bid % CHUNKS;
  const int b = nh >> 3, h = nh & 7;
  const int tid = threadIdx.x, wave = tid >> 6, lane = tid & 63;
  const int sub = lane >> 4, dq = lane & 15;
  const float4* k4 = (const float4*)kp;
  const int lbase = chunk * (L / CHUNKS) + wave * ROWS_PER_WAVE;
  int base4 = (b * L + lbase + sub) * 128 + h * 16 + dq;

  float ak0 = 0, ak1 = 0, ak2 = 0, ak3 = 0;
  for (int g = 0; g < GROUPS; ++g) {
    float4 kv = k4[base4];
    base4 += 512;  // 4 rows * 128 float4
    ak0 += sigm(kv.x); ak1 += sigm(kv.y); ak2 += sigm(kv.z); ak3 += sigm(kv.w);
  }
  REDW(ak0); REDW(ak1); REDW(ak2); REDW(ak3);
  if (lane < 16) {
    red[wave][dq][0] = ak0; red[wave][dq][1] = ak1;
    red[wave][dq][2] = ak2; red[wave][dq][3] = ak3;
  }
  __syncthreads();
  if (tid < 64) {  // tid = d; one coalesced atomic burst per block
    float s = red[0][tid >> 2][tid & 3] + red[1][tid >> 2][tid & 3] +
              red[2][tid >> 2][tid & 3] + red[3][tid >> 2][tid & 3];
    atomicAdd(&ws[OFF_KSUM + nh * 64 + tid], s);
  }
}

// P2: si = 1/dot(sq+e, ksum+e); qsum[d] += sq; qsi[d] += sq*si.
// (q only: 134 MB, regular -> primes L3; no qn stores, P4 recomputes.)
__global__ __launch_bounds__(256) void p2_flow(const float* __restrict__ qp,
                                               float* __restrict__ ws) {
  __shared__ float red[4][16][8];
  const int bid = blockIdx.x, nh = bid / CHUNKS, chunk = bid % CHUNKS;
  const int b = nh >> 3, h = nh & 7;
  const int tid = threadIdx.x, wave = tid >> 6, lane = tid & 63;
  const int sub = lane >> 4, dq = lane & 15;
  const float4* q4 = (const float4*)qp;
  const int lbase = chunk * (L / CHUNKS) + wave * ROWS_PER_WAVE;
  int base4 = (b * L + lbase + sub) * 128 + h * 16 + dq;

  const float* ksum = &ws[OFF_KSUM + nh * 64];
  const float ke0 = ksum[dq * 4 + 0] + FEPS, ke1 = ksum[dq * 4 + 1] + FEPS;
  const float ke2 = ksum[dq * 4 + 2] + FEPS, ke3 = ksum[dq * 4 + 3] + FEPS;

  float aq0 = 0, aq1 = 0, aq2 = 0, aq3 = 0;      // sum sq
  float aqs0 = 0, aqs1 = 0, aqs2 = 0, aqs3 = 0;  // sum qn
  for (int g = 0; g < GROUPS; ++g) {
    float4 qv = q4[base4];
    base4 += 512;
    float s0 = sigm(qv.x), s1 = sigm(qv.y), s2 = sigm(qv.z), s3 = sigm(qv.w);
    float t = (s0 + FEPS) * ke0 + (s1 + FEPS) * ke1 +
              (s2 + FEPS) * ke2 + (s3 + FEPS) * ke3;
    RED16(t);
    float si = 1.0f / t;  // row-critical: IEEE divide, once per 4 rows
    aq0 += s0; aq1 += s1; aq2 += s2; aq3 += s3;
    aqs0 += s0 * si; aqs1 += s1 * si; aqs2 += s2 * si; aqs3 += s3 * si;
  }
  REDW(aq0); REDW(aq1); REDW(aq2); REDW(aq3);
  REDW(aqs0); REDW(aqs1); REDW(aqs2); REDW(aqs3);
  if (lane < 16) {
    red[wave][dq][0] = aq0;  red[wave][dq][1] = aq1;
    red[wave][dq][2] = aq2;  red[wave][dq][3] = aq3;
    red[wave][dq][4] = aqs0; red[wave][dq][5] = aqs1;
    red[wave][dq][6] = aqs2; red[wave][dq][7] = aqs3;
  }
  __syncthreads();
  if (tid < 128) {  // tid<64: qsum[d=tid]; tid in [64,128): qsi[d=tid-64]
    int d = tid & 63, j = (tid >> 6) * 4 + (d & 3), dqi = d >> 2;
    float s = red[0][dqi][j] + red[1][dqi][j] + red[2][dqi][j] + red[3][dqi][j];
    int off = (tid < 64) ? OFF_QSUM : OFF_QSI;
    atomicAdd(&ws[off + nh * 64 + d], s);
  }
}

// P3: so = 1/dot(sk+e, qsum+e); kso[d] += sk*so;
//     cs = clip(dot(sk+e, qsi+e),-1,1); ex = exp(cs); SE += ex;
//     kvU[d][m] += sk[d]*ex*v[m]  (Lk/SE folded into P4).
// k = last use (nt), v = single use (nt): preserves q in L3 for P4.
__global__ __launch_bounds__(256) void p3_kv(const float* __restrict__ kp,
                                             const float* __restrict__ vp,
                                             float* __restrict__ ws) {
  // stg: 4 waves * 256 floats (in-wave transpose). combine: 64*65 padded
  // (stride 65 -> bank (lane+m)%32, 2-way = free; stride 64 was 64-way).
  __shared__ float smem[64 * 65];
  __shared__ float redk[4][16][4];
  const int bid = blockIdx.x, nh = bid / CHUNKS, chunk = bid % CHUNKS;
  const int b = nh >> 3, h = nh & 7;
  const int tid = threadIdx.x, wave = tid >> 6, lane = tid & 63;
  const int sub = lane >> 4, dq = lane & 15;
  const vf4* k4 = (const vf4*)kp;
  const vf4* v4 = (const vf4*)vp;
  const int lbase = chunk * (L / CHUNKS) + wave * ROWS_PER_WAVE;
  int base4 = (b * L + lbase + sub) * 128 + h * 16 + dq;
  const int vbase4 = (b * L + lbase) * 128 + h * 16;

  const float* qsi = &ws[OFF_QSI + nh * 64];
  const float e0 = qsi[dq * 4 + 0] + FEPS, e1 = qsi[dq * 4 + 1] + FEPS;
  const float e2 = qsi[dq * 4 + 2] + FEPS, e3 = qsi[dq * 4 + 3] + FEPS;
  const float* qsum = &ws[OFF_QSUM + nh * 64];
  const float qe0 = qsum[dq * 4 + 0] + FEPS, qe1 = qsum[dq * 4 + 1] + FEPS;
  const float qe2 = qsum[dq * 4 + 2] + FEPS, qe3 = qsum[dq * 4 + 3] + FEPS;

  float acc[64];
#pragma unroll
  for (int m = 0; m < 64; ++m) acc[m] = 0.0f;
  float se = 0.0f;
  float aks0 = 0, aks1 = 0, aks2 = 0, aks3 = 0;  // sum sk*so
  float* stg = &smem[wave * 256];

  for (int g = 0; g < GROUPS; ++g) {
    vf4 kv4 = ntload4(k4 + base4);
    base4 += 512;
    float s0 = sigm(kv4[0]), s1 = sigm(kv4[1]), s2 = sigm(kv4[2]), s3 = sigm(kv4[3]);
    // source_outgoing + kso accumulation
    float t2 = (s0 + FEPS) * qe0 + (s1 + FEPS) * qe1 +
               (s2 + FEPS) * qe2 + (s3 + FEPS) * qe3;
    RED16(t2);
    float so = 1.0f / t2;  // row-critical: IEEE divide
    aks0 += s0 * so; aks1 += s1 * so; aks2 += s2 * so; aks3 += s3 * so;
    // conserved_source -> softmax numerator
    float t = (s0 + FEPS) * e0 + (s1 + FEPS) * e1 +
              (s2 + FEPS) * e2 + (s3 + FEPS) * e3;
    RED16(t);
    t = fminf(fmaxf(t, -1.0f), 1.0f);
    float ex = __expf(t);
    if (dq == 0) se += ex;
    // stage kde (row sub, d = dq*4+c) for in-wave transpose
    vf4 kde4 = {s0 * ex, s1 * ex, s2 * ex, s3 * ex};
    ((vf4*)stg)[sub * 16 + dq] = kde4;
#pragma unroll
    for (int r = 0; r < 4; ++r) {
      float kde = stg[r * 64 + lane];                    // lane = d; 2-way banks
      const vf4* vr = v4 + vbase4 + (g * 4 + r) * 128;   // wave-uniform addr
#pragma unroll
      for (int j = 0; j < 16; ++j) {
        vf4 vv = ntload4(vr + j);
        acc[4 * j + 0] += kde * vv[0];
        acc[4 * j + 1] += kde * vv[1];
        acc[4 * j + 2] += kde * vv[2];
        acc[4 * j + 3] += kde * vv[3];
      }
    }
  }
  REDW(aks0); REDW(aks1); REDW(aks2); REDW(aks3);
  if (lane < 16) {
    redk[wave][dq][0] = aks0; redk[wave][dq][1] = aks1;
    redk[wave][dq][2] = aks2; redk[wave][dq][3] = aks3;
  }
  se += __shfl_xor(se, 1);  se += __shfl_xor(se, 2);  se += __shfl_xor(se, 4);
  se += __shfl_xor(se, 8);  se += __shfl_xor(se, 16); se += __shfl_xor(se, 32);
  if (lane == 0) atomicAdd(&ws[OFF_SE + nh], se);

  __syncthreads();
  if (tid < 64) {  // block-combined kso atomics (one burst per block)
    float s = redk[0][tid >> 2][tid & 3] + redk[1][tid >> 2][tid & 3] +
              redk[2][tid >> 2][tid & 3] + redk[3][tid >> 2][tid & 3];
    atomicAdd(&ws[OFF_KSO + nh * 64 + tid], s);
  }
  // combine the block's 4 wave-accumulators in LDS (padded stride 65),
  // then one coalesced atomic pass
  for (int r = 0; r < 4; ++r) {
    if (wave == r) {
      if (r == 0) {
#pragma unroll
        for (int m = 0; m < 64; ++m) smem[lane * 65 + m] = acc[m];
      } else {
#pragma unroll
        for (int m = 0; m < 64; ++m) smem[lane * 65 + m] += acc[m];
      }
    }
    __syncthreads();
  }
  float* kvg = &ws[OFF_KV + nh * 4096];
  for (int i = tid; i < 4096; i += 256)
    atomicAdd(&kvg[i], smem[(i >> 6) * 65 + (i & 63)]);
}

// P4: read q only (nt: last use). Recompute si/qn per row; in-wave LDS
// transpose gives each lane the full qn row (broadcast b128 reads).
//   sa = sigmoid(dot(sq+e, kso+e));  out = sa * (Lk/SE) * (qn . kvU)  (nt)
__global__ __launch_bounds__(256) void p4_out(const float* __restrict__ qp,
                                              float* __restrict__ outp,
                                              const float* __restrict__ ws) {
  __shared__ float stg[4 * 256];  // 4 waves * (4 rows * 64 d)
  const int bid = blockIdx.x, nh = bid / CHUNKS, chunk = bid % CHUNKS;
  const int b = nh >> 3, h = nh & 7;
  const int tid = threadIdx.x, wave = tid >> 6, lane = tid & 63;
  const int sub = lane >> 4, dq = lane & 15;
  const vf4* q4 = (const vf4*)qp;
  const int lbase = chunk * (L / CHUNKS) + wave * ROWS_PER_WAVE;
  int base4 = (b * L + lbase + sub) * 128 + h * 16 + dq;
  const int obase = (b * L + lbase) * 512 + h * 64;

  const float* ksum = &ws[OFF_KSUM + nh * 64];
  const float ke0 = ksum[dq * 4 + 0] + FEPS, ke1 = ksum[dq * 4 + 1] + FEPS;
  const float ke2 = ksum[dq * 4 + 2] + FEPS, ke3 = ksum[dq * 4 + 3] + FEPS;
  const float* kso = &ws[OFF_KSO + nh * 64];
  const float ko0 = kso[dq * 4 + 0] + FEPS, ko1 = kso[dq * 4 + 1] + FEPS;
  const float ko2 = kso[dq * 4 + 2] + FEPS, ko3 = kso[dq * 4 + 3] + FEPS;
  const float scale = 8192.0f / ws[OFF_SE + nh];

  float kvcol[64];  // column `lane` of kv, pre-scaled by Lk/SE
  const float* kvg = &ws[OFF_KV + nh * 4096];
#pragma unroll
  for (int d = 0; d < 64; ++d) kvcol[d] = kvg[d * 64 + lane] * scale;

  float* sw = &stg[wave * 256];
  vf4* sw4 = (vf4*)sw;

  for (int g = 0; g < GROUPS; ++g) {
    vf4 qv = ntload4(q4 + base4);
    base4 += 512;
    float s0 = sigm(qv[0]), s1 = sigm(qv[1]), s2 = sigm(qv[2]), s3 = sigm(qv[3]);
    // sink_incoming for this row
    float t = (s0 + FEPS) * ke0 + (s1 + FEPS) * ke1 +
              (s2 + FEPS) * ke2 + (s3 + FEPS) * ke3;
    RED16(t);
    float si = 1.0f / t;  // row-critical: IEEE divide
    // sink_allocation (Lq/Lk == 1)
    float tp = (s0 + FEPS) * ko0 + (s1 + FEPS) * ko1 +
               (s2 + FEPS) * ko2 + (s3 + FEPS) * ko3;
    RED16(tp);
    float sa = sigm(tp);
    float sa0 = __shfl(sa, 0), sa1 = __shfl(sa, 16);
    float sa2 = __shfl(sa, 32), sa3 = __shfl(sa, 48);
    // stage qn (contiguous: float4 index sub*16+dq spans 0..63)
    vf4 qn4 = {s0 * si, s1 * si, s2 * si, s3 * si};
    sw4[sub * 16 + dq] = qn4;
#pragma unroll
    for (int r = 0; r < 4; ++r) {
      const vf4* qr = (const vf4*)(sw + r * 64);  // broadcast reads
      float a = 0.0f;
#pragma unroll
      for (int j = 0; j < 16; ++j) {
        vf4 nn = qr[j];
        a += nn[0] * kvcol[4 * j + 0] + nn[1] * kvcol[4 * j + 1] +
             nn[2] * kvcol[4 * j + 2] + nn[3] * kvcol[4 * j + 3];
      }
      float sar = (r == 0) ? sa0 : (r == 1) ? sa1 : (r == 2) ? sa2 : sa3;
      __builtin_nontemporal_store(a * sar, &outp[obase + (g * 4 + r) * 512 + lane]);
    }
  }
}

extern "C" void kernel_launch(void* const* d_in, const int* in_sizes, int n_in,
                              void* d_out, int out_size, void* d_ws, size_t ws_size,
                              hipStream_t stream) {
  const float* q = (const float*)d_in[0];
  const float* k = (const float*)d_in[1];
  const float* v = (const float*)d_in[2];
  float* out = (float*)d_out;
  float* ws = (float*)d_ws;

  // async memset is graph-capture-legal (harness uses it for re-poison);
  // replaces the p0_zero kernel launch.
  hipMemsetAsync(ws, 0, (size_t)WS_FLOATS * sizeof(float), stream);

  const int grid = NH * CHUNKS;  // 1024 blocks of 256 threads
  hipLaunchKernelGGL(p1_ksum, dim3(grid), dim3(256), 0, stream, k, ws);
  hipLaunchKernelGGL(p2_flow, dim3(grid), dim3(256), 0, stream, q, ws);
  hipLaunchKernelGGL(p3_kv,   dim3(grid), dim3(256), 0, stream, k, v, ws);
  hipLaunchKernelGGL(p4_out,  dim3(grid), dim3(256), 0, stream, q, out, ws);
}